// Round 11
// baseline (124.537 us; speedup 1.0000x reference)
//
#include <hip/hip_runtime.h>
#include <hip/hip_fp16.h>

#define B_ 128
#define T_ 512
#define VT_ 2048
#define E_ 1024
#define D_ 1024

typedef _Float16 h8 __attribute__((ext_vector_type(8)));
typedef float f4 __attribute__((ext_vector_type(4)));

#define C2LE 2.8853900817779268f  // 2*log2(e)
#define L2E  1.4426950408889634f

static __device__ __forceinline__ float rcpf(float x) { return __builtin_amdgcn_rcpf(x); }
static __device__ __forceinline__ float ex2(float x)  { return __builtin_amdgcn_exp2f(x); }

// ---------------- workspace layout ----------------
// R  : float[640][1024]   X (rows 0-127, no bias) and Y (rows 128-639); gemm atomically accumulates
// SP : float[8][128][512] per-d-chunk score partials
// pA : f16[640*2048]      A fragments (KB-dim 64)
// pB : f16[1M + 1M + 2M]  W_h^T, W_e^T, W_t^T fragments
#define R_FLOATS   (640 * 1024)
#define SP_FLOATS  (8 * 128 * 512)
#define PA_HALVES  (640 * 2048)
#define PB_WH      0
#define PB_WE      1048576
#define PB_WT      2097152

// ---------- coalesced pack: 64x64 fp32 panel -> f16 MFMA fragments ----------
// A panel: rows = m (4 mb of 16), cols = k (2 kb of 32). Frag lane r=lane&15 -> m, g=lane>>4: k=g*8+j.
__device__ __forceinline__ void pack_panelA(const float* __restrict__ src, int ld,
                                            _Float16* __restrict__ dst, int mb_off, int kb_off,
                                            int pm, int pk, int tid, float lds[64][72])
{
    #pragma unroll
    for (int p = 0; p < 4; ++p) {
        int row = (tid >> 4) + p * 16, col = (tid & 15) * 4;
        *(f4*)&lds[row][col] = *(const f4*)&src[(size_t)(pm * 64 + row) * ld + pk * 64 + col];
    }
    __syncthreads();
    #pragma unroll
    for (int w = 0; w < 2; ++w) {
        int fl = w * 256 + tid;
        int f = fl >> 6, lane = fl & 63;
        int i = f >> 1, k2 = f & 1;
        int r = lane & 15, g = lane >> 4;
        const float* p = &lds[i * 16 + r][k2 * 32 + g * 8];
        h8 h;
        #pragma unroll
        for (int j = 0; j < 8; ++j) h[j] = (_Float16)p[j];
        int MB = mb_off + pm * 4 + i;
        int KB = kb_off + pk * 2 + k2;
        *(h8*)(dst + ((size_t)(MB * 64 + KB) * 64 + lane) * 8) = h;
    }
}

// B panel from W[K][1024]: rows = k (2 kb of 32), cols = n (4 nb of 16). Frag: n=r, k=g*8+j (transposed).
__device__ __forceinline__ void pack_panelB(const float* __restrict__ W,
                                            _Float16* __restrict__ dst, int KBdim,
                                            int pk, int pn, int tid, float lds[64][72])
{
    #pragma unroll
    for (int p = 0; p < 4; ++p) {
        int row = (tid >> 4) + p * 16, col = (tid & 15) * 4;
        *(f4*)&lds[row][col] = *(const f4*)&W[(size_t)(pk * 64 + row) * 1024 + pn * 64 + col];
    }
    __syncthreads();
    #pragma unroll
    for (int w = 0; w < 2; ++w) {
        int fl = w * 256 + tid;
        int f = fl >> 6, lane = fl & 63;
        int j = f >> 1, i2 = f & 1;
        int r = lane & 15, g = lane >> 4;
        h8 h;
        #pragma unroll
        for (int jj = 0; jj < 8; ++jj) h[jj] = (_Float16)lds[i2 * 32 + g * 8 + jj][j * 16 + r];
        int NB = pn * 4 + j;
        int KB = pk * 2 + i2;
        *(h8*)(dst + ((size_t)(NB * KBdim + KB) * 64 + lane) * 8) = h;
    }
}

__global__ __launch_bounds__(256) void pack_kernel(
    const float* __restrict__ hidden, const float* __restrict__ topic,
    const float* __restrict__ enc,
    const float* __restrict__ W_h, const float* __restrict__ W_t, const float* __restrict__ W_e,
    _Float16* __restrict__ pA, _Float16* __restrict__ pB)
{
    __shared__ float lds[64][72];
    const int bid = blockIdx.x, tid = threadIdx.x;
    if (bid < 32) {                         // hidden [128][1024] -> A kb 0..31
        int b = bid;        pack_panelA(hidden, 1024, pA, 0,  0, b >> 4, b & 15, tid, lds);
    } else if (bid < 64) {                  // enc [128][1024] -> A kb 32..63
        int b = bid - 32;   pack_panelA(enc,    1024, pA, 0, 32, b >> 4, b & 15, tid, lds);
    } else if (bid < 320) {                 // topic [512][2048] -> A mb 8..39
        int b = bid - 64;   pack_panelA(topic,  2048, pA, 8,  0, b >> 5, b & 31, tid, lds);
    } else if (bid < 576) {                 // W_h [1024][1024]
        int b = bid - 320;  pack_panelB(W_h, pB + PB_WH, 32, b >> 4, b & 15, tid, lds);
    } else if (bid < 832) {                 // W_e
        int b = bid - 576;  pack_panelB(W_e, pB + PB_WE, 32, b >> 4, b & 15, tid, lds);
    } else {                                // W_t [2048][1024]
        int b = bid - 832;  pack_panelB(W_t, pB + PB_WT, 64, b >> 4, b & 15, tid, lds);
    }
}

// fused GEMM, split-K=8, wave tile 32x64 (acc 2x4), XCD-swizzled so each XCD owns one
// K-slice s (A 327KB + B <=512KB fits its private L2). Epilogue: atomicAdd into R.
__global__ __launch_bounds__(256, 3) void gemm_kernel(const _Float16* __restrict__ pA,
                                                      const _Float16* __restrict__ pB,
                                                      float* __restrict__ R)
{
    // bijective XCD swizzle: nwg=640, all blocks with lin%8==c get s=c
    const int lin = blockIdx.x;
    const int sw  = (lin & 7) * 80 + (lin >> 3);
    const int s   = sw / 80;
    const int rem = sw % 80;
    const int mt  = rem % 10;
    const int nt  = rem / 10;

    const int tid = threadIdx.x, wave = tid >> 6, lane = tid & 63;
    const int wm = (wave >> 1) * 32;   // 0 or 32
    const int wn = (wave & 1) * 64;    // 0 or 64
    const int r = lane & 15, g = lane >> 4;

    const int mb0 = mt * 4 + (wm >> 4);
    const int nb0 = (nt * 128 + wn) >> 4;
    const int kb0 = s * 8;

    const _Float16* Bp; int KB_B, kbB0;
    if (mt < 2) {  // X rows: s<4 -> hidden@W_h (A kb 0..31), s>=4 -> enc@W_e (A kb 32..63)
        if (kb0 < 32) { Bp = pB + PB_WH; kbB0 = kb0; }
        else          { Bp = pB + PB_WE; kbB0 = kb0 - 32; }
        KB_B = 32;
    } else { Bp = pB + PB_WT; kbB0 = kb0; KB_B = 64; }

    const _Float16* Ap = pA + ((size_t)(mb0 * 64 + kb0) * 64 + lane) * 8;
    const _Float16* Bq = Bp + ((size_t)(nb0 * KB_B + kbB0) * 64 + lane) * 8;
    const size_t aStrM = (size_t)64 * 512;        // mb -> mb+1
    const size_t bStrN = (size_t)KB_B * 512;      // nb -> nb+1

    f4 acc[2][4] = {};
    #pragma unroll
    for (int ks = 0; ks < 8; ++ks) {
        h8 a0 = *(const h8*)(Ap + (size_t)ks * 512);
        h8 a1 = *(const h8*)(Ap + aStrM + (size_t)ks * 512);
        h8 b0 = *(const h8*)(Bq + (size_t)ks * 512);
        h8 b1 = *(const h8*)(Bq + bStrN + (size_t)ks * 512);
        h8 b2 = *(const h8*)(Bq + 2 * bStrN + (size_t)ks * 512);
        h8 b3 = *(const h8*)(Bq + 3 * bStrN + (size_t)ks * 512);
        acc[0][0] = __builtin_amdgcn_mfma_f32_16x16x32_f16(a0, b0, acc[0][0], 0, 0, 0);
        acc[0][1] = __builtin_amdgcn_mfma_f32_16x16x32_f16(a0, b1, acc[0][1], 0, 0, 0);
        acc[0][2] = __builtin_amdgcn_mfma_f32_16x16x32_f16(a0, b2, acc[0][2], 0, 0, 0);
        acc[0][3] = __builtin_amdgcn_mfma_f32_16x16x32_f16(a0, b3, acc[0][3], 0, 0, 0);
        acc[1][0] = __builtin_amdgcn_mfma_f32_16x16x32_f16(a1, b0, acc[1][0], 0, 0, 0);
        acc[1][1] = __builtin_amdgcn_mfma_f32_16x16x32_f16(a1, b1, acc[1][1], 0, 0, 0);
        acc[1][2] = __builtin_amdgcn_mfma_f32_16x16x32_f16(a1, b2, acc[1][2], 0, 0, 0);
        acc[1][3] = __builtin_amdgcn_mfma_f32_16x16x32_f16(a1, b3, acc[1][3], 0, 0, 0);
    }

    // C/D layout: col = lane&15, row = (lane>>4)*4 + q; accumulate across the 8 K-slices
    float* Rp = R + ((size_t)(mt * 64 + wm + g * 4)) * 1024 + nt * 128 + wn + r;
    #pragma unroll
    for (int i = 0; i < 2; ++i)
        #pragma unroll
        for (int j = 0; j < 4; ++j)
            #pragma unroll
            for (int q = 0; q < 4; ++q)
                atomicAdd(&Rp[(size_t)(i * 16 + q) * 1024 + j * 16], C2LE * acc[i][j][q]);
}

// SP[z][b][t] = sum_{d in chunk z} v_d * rcp(exp2(X+Y) + 1);  X gets C2LE*bias here.
__global__ __launch_bounds__(256) void score_kernel(const float* __restrict__ R,
                                                    const float* __restrict__ bias,
                                                    const float* __restrict__ v,
                                                    float* __restrict__ SP)
{
    __shared__ float Xs[16][128];   // XOR-16 swizzle on 16B units
    __shared__ float Ys[64][128];
    __shared__ float vs[128];

    const int tid = threadIdx.x;
    const int b0 = blockIdx.x * 16;
    const int t0 = blockIdx.y * 64;
    const int d0 = blockIdx.z * 128;

    #pragma unroll
    for (int i = 0; i < 8; ++i) {
        int idx = tid + i * 256;
        int row = idx >> 5, c4 = idx & 31;
        f4 vv = *(const f4*)&R[(size_t)(128 + t0 + row) * 1024 + d0 + c4 * 4];
        *(f4*)&Ys[row][(c4 ^ (row & 15)) * 4] = vv;
    }
    #pragma unroll
    for (int i = 0; i < 2; ++i) {
        int idx = tid + i * 256;
        int row = idx >> 5, c4 = idx & 31;
        f4 vv = *(const f4*)&R[(size_t)(b0 + row) * 1024 + d0 + c4 * 4];
        f4 bb = *(const f4*)&bias[d0 + c4 * 4];
        vv += bb * C2LE;
        *(f4*)&Xs[row][(c4 ^ (row & 15)) * 4] = vv;
    }
    if (tid < 32) *(f4*)&vs[tid * 4] = *(const f4*)&v[d0 + tid * 4];
    __syncthreads();

    const int tq = tid & 31, bq = tid >> 5;
    const int sx0 = bq & 15, sx1 = (bq + 8) & 15, sy = tq & 15;
    float a00 = 0.f, a01 = 0.f, a10 = 0.f, a11 = 0.f;

    for (int dd = 0; dd < 32; ++dd) {
        f4 xa = *(const f4*)&Xs[bq]     [(dd ^ sx0) * 4];
        f4 xb = *(const f4*)&Xs[bq + 8] [(dd ^ sx1) * 4];
        f4 ya = *(const f4*)&Ys[tq]     [(dd ^ sy) * 4];
        f4 yb = *(const f4*)&Ys[tq + 32][(dd ^ sy) * 4];
        f4 vv = *(const f4*)&vs[dd * 4];
        #pragma unroll
        for (int j = 0; j < 4; ++j) {
            float e;
            e = ex2(xa[j] + ya[j]); a00 += vv[j] * rcpf(e + 1.0f);
            e = ex2(xa[j] + yb[j]); a01 += vv[j] * rcpf(e + 1.0f);
            e = ex2(xb[j] + ya[j]); a10 += vv[j] * rcpf(e + 1.0f);
            e = ex2(xb[j] + yb[j]); a11 += vv[j] * rcpf(e + 1.0f);
        }
    }

    float* sp = SP + (size_t)blockIdx.z * (B_ * T_);
    sp[(size_t)(b0 + bq)     * T_ + t0 + tq]      = a00;
    sp[(size_t)(b0 + bq)     * T_ + t0 + tq + 32] = a01;
    sp[(size_t)(b0 + bq + 8) * T_ + t0 + tq]      = a10;
    sp[(size_t)(b0 + bq + 8) * T_ + t0 + tq + 32] = a11;
}

// softmax over t of score = -2 * sum_z SP[z][b][t]  (constant sum(v) cancels)
__global__ __launch_bounds__(256) void softmax_kernel(
    const float* __restrict__ SP, float* __restrict__ out)
{
    const int b = blockIdx.x, tid = threadIdx.x;
    float s0 = 0.f, s1 = 0.f;
    #pragma unroll
    for (int z = 0; z < 8; ++z) {
        s0 += SP[(size_t)z * B_ * T_ + (size_t)b * T_ + tid];
        s1 += SP[(size_t)z * B_ * T_ + (size_t)b * T_ + tid + 256];
    }
    s0 *= -2.0f; s1 *= -2.0f;

    float m = fmaxf(s0, s1);
    #pragma unroll
    for (int off = 32; off >= 1; off >>= 1) m = fmaxf(m, __shfl_xor(m, off));
    __shared__ float red[4];
    __shared__ float red2[4];
    const int wv = tid >> 6;
    if ((tid & 63) == 0) red[wv] = m;
    __syncthreads();
    m = fmaxf(fmaxf(red[0], red[1]), fmaxf(red[2], red[3]));

    float e0 = ex2((s0 - m) * L2E);
    float e1 = ex2((s1 - m) * L2E);
    float sum = e0 + e1;
    #pragma unroll
    for (int off = 32; off >= 1; off >>= 1) sum += __shfl_xor(sum, off);
    if ((tid & 63) == 0) red2[wv] = sum;
    __syncthreads();
    sum = red2[0] + red2[1] + red2[2] + red2[3];

    const float rs = rcpf(sum);
    out[(size_t)b * T_ + tid]       = e0 * rs;
    out[(size_t)b * T_ + tid + 256] = e1 * rs;
}

extern "C" void kernel_launch(void* const* d_in, const int* in_sizes, int n_in,
                              void* d_out, int out_size, void* d_ws, size_t ws_size,
                              hipStream_t stream)
{
    const float* hidden = (const float*)d_in[0];
    const float* topic  = (const float*)d_in[1];
    const float* enc    = (const float*)d_in[2];
    const float* W_h    = (const float*)d_in[3];
    const float* W_t    = (const float*)d_in[4];
    const float* W_e    = (const float*)d_in[5];
    const float* bvec   = (const float*)d_in[6];
    const float* vvec   = (const float*)d_in[7];
    float* out = (float*)d_out;

    float* R      = (float*)d_ws;
    float* SPb    = R + R_FLOATS;
    _Float16* pA  = (_Float16*)(SPb + SP_FLOATS);
    _Float16* pB  = pA + PA_HALVES;

    (void)hipMemsetAsync(R, 0, R_FLOATS * sizeof(float), stream);
    pack_kernel<<<1344, 256, 0, stream>>>(hidden, topic, enc, W_h, W_t, W_e, pA, pB);
    gemm_kernel<<<640, 256, 0, stream>>>(pA, pB, R);
    score_kernel<<<dim3(8, 8, 8), 256, 0, stream>>>(R, bvec, vvec, SPb);
    softmax_kernel<<<128, 256, 0, stream>>>(SPb, out);
}

// Round 12
// 115.832 us; speedup vs baseline: 1.0752x; 1.0752x over previous
//
#include <hip/hip_runtime.h>
#include <hip/hip_fp16.h>

#define B_ 128
#define T_ 512
#define VT_ 2048
#define E_ 1024
#define D_ 1024

typedef _Float16 h8 __attribute__((ext_vector_type(8)));
typedef float f4 __attribute__((ext_vector_type(4)));

#define C2LE 2.8853900817779268f  // 2*log2(e)
#define L2E  1.4426950408889634f

static __device__ __forceinline__ float rcpf(float x) { return __builtin_amdgcn_rcpf(x); }
static __device__ __forceinline__ float ex2(float x)  { return __builtin_amdgcn_exp2f(x); }

// ---------------- workspace layout ----------------
// P  : float[8][640][1024]  split-K partials (rows 0-127 = X, 128-639 = Y)
// R  : float[640][1024]     reduced (+ C2LE*bias on X rows)
// SP : float[8][128][512]   per-d-chunk score partials
// pA : f16[640*2048]        A fragments (KB-dim 64)
// pB : f16[1M + 1M + 2M]    W_h^T, W_e^T, W_t^T fragments
#define P_FLOATS   (8 * 640 * 1024)
#define R_FLOATS   (640 * 1024)
#define SP_FLOATS  (8 * 128 * 512)
#define PA_HALVES  (640 * 2048)
#define PB_WH      0
#define PB_WE      1048576
#define PB_WT      2097152

// ---------- coalesced pack: 64x64 fp32 panel -> f16 MFMA fragments ----------
// A panel: rows = m (4 mb of 16), cols = k (2 kb of 32). Frag lane r=lane&15 -> m, g=lane>>4: k=g*8+j.
__device__ __forceinline__ void pack_panelA(const float* __restrict__ src, int ld,
                                            _Float16* __restrict__ dst, int mb_off, int kb_off,
                                            int pm, int pk, int tid, float lds[64][72])
{
    #pragma unroll
    for (int p = 0; p < 4; ++p) {
        int row = (tid >> 4) + p * 16, col = (tid & 15) * 4;
        *(f4*)&lds[row][col] = *(const f4*)&src[(size_t)(pm * 64 + row) * ld + pk * 64 + col];
    }
    __syncthreads();
    #pragma unroll
    for (int w = 0; w < 2; ++w) {
        int fl = w * 256 + tid;
        int f = fl >> 6, lane = fl & 63;
        int i = f >> 1, k2 = f & 1;
        int r = lane & 15, g = lane >> 4;
        const float* p = &lds[i * 16 + r][k2 * 32 + g * 8];
        h8 h;
        #pragma unroll
        for (int j = 0; j < 8; ++j) h[j] = (_Float16)p[j];
        int MB = mb_off + pm * 4 + i;
        int KB = kb_off + pk * 2 + k2;
        *(h8*)(dst + ((size_t)(MB * 64 + KB) * 64 + lane) * 8) = h;
    }
}

// B panel from W[K][1024]: rows = k (2 kb of 32), cols = n (4 nb of 16). Frag: n=r, k=g*8+j (transposed).
__device__ __forceinline__ void pack_panelB(const float* __restrict__ W,
                                            _Float16* __restrict__ dst, int KBdim,
                                            int pk, int pn, int tid, float lds[64][72])
{
    #pragma unroll
    for (int p = 0; p < 4; ++p) {
        int row = (tid >> 4) + p * 16, col = (tid & 15) * 4;
        *(f4*)&lds[row][col] = *(const f4*)&W[(size_t)(pk * 64 + row) * 1024 + pn * 64 + col];
    }
    __syncthreads();
    #pragma unroll
    for (int w = 0; w < 2; ++w) {
        int fl = w * 256 + tid;
        int f = fl >> 6, lane = fl & 63;
        int j = f >> 1, i2 = f & 1;
        int r = lane & 15, g = lane >> 4;
        h8 h;
        #pragma unroll
        for (int jj = 0; jj < 8; ++jj) h[jj] = (_Float16)lds[i2 * 32 + g * 8 + jj][j * 16 + r];
        int NB = pn * 4 + j;
        int KB = pk * 2 + i2;
        *(h8*)(dst + ((size_t)(NB * KBdim + KB) * 64 + lane) * 8) = h;
    }
}

__global__ __launch_bounds__(256) void pack_kernel(
    const float* __restrict__ hidden, const float* __restrict__ topic,
    const float* __restrict__ enc,
    const float* __restrict__ W_h, const float* __restrict__ W_t, const float* __restrict__ W_e,
    _Float16* __restrict__ pA, _Float16* __restrict__ pB)
{
    __shared__ float lds[64][72];
    const int bid = blockIdx.x, tid = threadIdx.x;
    if (bid < 32) {                         // hidden [128][1024] -> A kb 0..31
        int b = bid;        pack_panelA(hidden, 1024, pA, 0,  0, b >> 4, b & 15, tid, lds);
    } else if (bid < 64) {                  // enc [128][1024] -> A kb 32..63
        int b = bid - 32;   pack_panelA(enc,    1024, pA, 0, 32, b >> 4, b & 15, tid, lds);
    } else if (bid < 320) {                 // topic [512][2048] -> A mb 8..39
        int b = bid - 64;   pack_panelA(topic,  2048, pA, 8,  0, b >> 5, b & 31, tid, lds);
    } else if (bid < 576) {                 // W_h [1024][1024]
        int b = bid - 320;  pack_panelB(W_h, pB + PB_WH, 32, b >> 4, b & 15, tid, lds);
    } else if (bid < 832) {                 // W_e
        int b = bid - 576;  pack_panelB(W_e, pB + PB_WE, 32, b >> 4, b & 15, tid, lds);
    } else {                                // W_t [2048][1024]
        int b = bid - 832;  pack_panelB(W_t, pB + PB_WT, 64, b >> 4, b & 15, tid, lds);
    }
}

// fused GEMM, split-K=8, wave tile 32x64 (acc 2x4), XCD-swizzled so each XCD owns one
// K-slice s (A 327KB + B <=512KB fits its private L2). Plain stores to P (no atomics).
__global__ __launch_bounds__(256, 3) void gemm_kernel(const _Float16* __restrict__ pA,
                                                      const _Float16* __restrict__ pB,
                                                      float* __restrict__ P)
{
    // bijective XCD swizzle: nwg=640, all blocks with lin%8==c get s=c
    const int lin = blockIdx.x;
    const int sw  = (lin & 7) * 80 + (lin >> 3);
    const int s   = sw / 80;
    const int rem = sw % 80;
    const int mt  = rem % 10;
    const int nt  = rem / 10;

    const int tid = threadIdx.x, wave = tid >> 6, lane = tid & 63;
    const int wm = (wave >> 1) * 32;   // 0 or 32
    const int wn = (wave & 1) * 64;    // 0 or 64
    const int r = lane & 15, g = lane >> 4;

    const int mb0 = mt * 4 + (wm >> 4);
    const int nb0 = (nt * 128 + wn) >> 4;
    const int kb0 = s * 8;

    const _Float16* Bp; int KB_B, kbB0;
    if (mt < 2) {  // X rows: s<4 -> hidden@W_h (A kb 0..31), s>=4 -> enc@W_e (A kb 32..63)
        if (kb0 < 32) { Bp = pB + PB_WH; kbB0 = kb0; }
        else          { Bp = pB + PB_WE; kbB0 = kb0 - 32; }
        KB_B = 32;
    } else { Bp = pB + PB_WT; kbB0 = kb0; KB_B = 64; }

    const _Float16* Ap = pA + ((size_t)(mb0 * 64 + kb0) * 64 + lane) * 8;
    const _Float16* Bq = Bp + ((size_t)(nb0 * KB_B + kbB0) * 64 + lane) * 8;
    const size_t aStrM = (size_t)64 * 512;        // mb -> mb+1
    const size_t bStrN = (size_t)KB_B * 512;      // nb -> nb+1

    f4 acc[2][4] = {};
    #pragma unroll
    for (int ks = 0; ks < 8; ++ks) {
        h8 a0 = *(const h8*)(Ap + (size_t)ks * 512);
        h8 a1 = *(const h8*)(Ap + aStrM + (size_t)ks * 512);
        h8 b0 = *(const h8*)(Bq + (size_t)ks * 512);
        h8 b1 = *(const h8*)(Bq + bStrN + (size_t)ks * 512);
        h8 b2 = *(const h8*)(Bq + 2 * bStrN + (size_t)ks * 512);
        h8 b3 = *(const h8*)(Bq + 3 * bStrN + (size_t)ks * 512);
        acc[0][0] = __builtin_amdgcn_mfma_f32_16x16x32_f16(a0, b0, acc[0][0], 0, 0, 0);
        acc[0][1] = __builtin_amdgcn_mfma_f32_16x16x32_f16(a0, b1, acc[0][1], 0, 0, 0);
        acc[0][2] = __builtin_amdgcn_mfma_f32_16x16x32_f16(a0, b2, acc[0][2], 0, 0, 0);
        acc[0][3] = __builtin_amdgcn_mfma_f32_16x16x32_f16(a0, b3, acc[0][3], 0, 0, 0);
        acc[1][0] = __builtin_amdgcn_mfma_f32_16x16x32_f16(a1, b0, acc[1][0], 0, 0, 0);
        acc[1][1] = __builtin_amdgcn_mfma_f32_16x16x32_f16(a1, b1, acc[1][1], 0, 0, 0);
        acc[1][2] = __builtin_amdgcn_mfma_f32_16x16x32_f16(a1, b2, acc[1][2], 0, 0, 0);
        acc[1][3] = __builtin_amdgcn_mfma_f32_16x16x32_f16(a1, b3, acc[1][3], 0, 0, 0);
    }

    // C/D layout: col = lane&15, row = (lane>>4)*4 + q
    float* Pp = P + ((size_t)s * 640 + mt * 64 + wm + g * 4) * 1024 + nt * 128 + wn + r;
    #pragma unroll
    for (int i = 0; i < 2; ++i)
        #pragma unroll
        for (int j = 0; j < 4; ++j)
            #pragma unroll
            for (int q = 0; q < 4; ++q)
                Pp[(size_t)(i * 16 + q) * 1024 + j * 16] = C2LE * acc[i][j][q];
}

// R[row][d] = sum_z P[z][row][d] + (row<128 ? C2LE*bias[d] : 0)
__global__ __launch_bounds__(256) void reduce_kernel(const float* __restrict__ P,
                                                     const float* __restrict__ bias,
                                                     float* __restrict__ R)
{
    const int row = blockIdx.x, tid = threadIdx.x;
    const size_t off = (size_t)row * 1024 + tid * 4;
    const size_t PS = (size_t)640 * 1024;
    f4 acc = *(const f4*)&P[off];
    #pragma unroll
    for (int z = 1; z < 8; ++z) acc += *(const f4*)&P[off + (size_t)z * PS];
    if (row < 128) {
        f4 bb = *(const f4*)&bias[tid * 4];
        acc += bb * C2LE;
    }
    *(f4*)&R[off] = acc;
}

// SP[z][b][t] = sum_{d in chunk z} v_d * rcp(exp2(X+Y) + 1)
__global__ __launch_bounds__(256) void score_kernel(const float* __restrict__ R,
                                                    const float* __restrict__ v,
                                                    float* __restrict__ SP)
{
    __shared__ float Xs[16][128];   // XOR-16 swizzle on 16B units
    __shared__ float Ys[64][128];
    __shared__ float vs[128];

    const int tid = threadIdx.x;
    const int b0 = blockIdx.x * 16;
    const int t0 = blockIdx.y * 64;
    const int d0 = blockIdx.z * 128;

    #pragma unroll
    for (int i = 0; i < 8; ++i) {
        int idx = tid + i * 256;
        int row = idx >> 5, c4 = idx & 31;
        f4 vv = *(const f4*)&R[(size_t)(128 + t0 + row) * 1024 + d0 + c4 * 4];
        *(f4*)&Ys[row][(c4 ^ (row & 15)) * 4] = vv;
    }
    #pragma unroll
    for (int i = 0; i < 2; ++i) {
        int idx = tid + i * 256;
        int row = idx >> 5, c4 = idx & 31;
        f4 vv = *(const f4*)&R[(size_t)(b0 + row) * 1024 + d0 + c4 * 4];
        *(f4*)&Xs[row][(c4 ^ (row & 15)) * 4] = vv;
    }
    if (tid < 32) *(f4*)&vs[tid * 4] = *(const f4*)&v[d0 + tid * 4];
    __syncthreads();

    const int tq = tid & 31, bq = tid >> 5;
    const int sx0 = bq & 15, sx1 = (bq + 8) & 15, sy = tq & 15;
    float a00 = 0.f, a01 = 0.f, a10 = 0.f, a11 = 0.f;

    for (int dd = 0; dd < 32; ++dd) {
        f4 xa = *(const f4*)&Xs[bq]     [(dd ^ sx0) * 4];
        f4 xb = *(const f4*)&Xs[bq + 8] [(dd ^ sx1) * 4];
        f4 ya = *(const f4*)&Ys[tq]     [(dd ^ sy) * 4];
        f4 yb = *(const f4*)&Ys[tq + 32][(dd ^ sy) * 4];
        f4 vv = *(const f4*)&vs[dd * 4];
        #pragma unroll
        for (int j = 0; j < 4; ++j) {
            float e;
            e = ex2(xa[j] + ya[j]); a00 += vv[j] * rcpf(e + 1.0f);
            e = ex2(xa[j] + yb[j]); a01 += vv[j] * rcpf(e + 1.0f);
            e = ex2(xb[j] + ya[j]); a10 += vv[j] * rcpf(e + 1.0f);
            e = ex2(xb[j] + yb[j]); a11 += vv[j] * rcpf(e + 1.0f);
        }
    }

    float* sp = SP + (size_t)blockIdx.z * (B_ * T_);
    sp[(size_t)(b0 + bq)     * T_ + t0 + tq]      = a00;
    sp[(size_t)(b0 + bq)     * T_ + t0 + tq + 32] = a01;
    sp[(size_t)(b0 + bq + 8) * T_ + t0 + tq]      = a10;
    sp[(size_t)(b0 + bq + 8) * T_ + t0 + tq + 32] = a11;
}

// softmax over t of score = -2 * sum_z SP[z][b][t]  (constant sum(v) cancels)
__global__ __launch_bounds__(256) void softmax_kernel(
    const float* __restrict__ SP, float* __restrict__ out)
{
    const int b = blockIdx.x, tid = threadIdx.x;
    float s0 = 0.f, s1 = 0.f;
    #pragma unroll
    for (int z = 0; z < 8; ++z) {
        s0 += SP[(size_t)z * B_ * T_ + (size_t)b * T_ + tid];
        s1 += SP[(size_t)z * B_ * T_ + (size_t)b * T_ + tid + 256];
    }
    s0 *= -2.0f; s1 *= -2.0f;

    float m = fmaxf(s0, s1);
    #pragma unroll
    for (int off = 32; off >= 1; off >>= 1) m = fmaxf(m, __shfl_xor(m, off));
    __shared__ float red[4];
    __shared__ float red2[4];
    const int wv = tid >> 6;
    if ((tid & 63) == 0) red[wv] = m;
    __syncthreads();
    m = fmaxf(fmaxf(red[0], red[1]), fmaxf(red[2], red[3]));

    float e0 = ex2((s0 - m) * L2E);
    float e1 = ex2((s1 - m) * L2E);
    float sum = e0 + e1;
    #pragma unroll
    for (int off = 32; off >= 1; off >>= 1) sum += __shfl_xor(sum, off);
    if ((tid & 63) == 0) red2[wv] = sum;
    __syncthreads();
    sum = red2[0] + red2[1] + red2[2] + red2[3];

    const float rs = rcpf(sum);
    out[(size_t)b * T_ + tid]       = e0 * rs;
    out[(size_t)b * T_ + tid + 256] = e1 * rs;
}

extern "C" void kernel_launch(void* const* d_in, const int* in_sizes, int n_in,
                              void* d_out, int out_size, void* d_ws, size_t ws_size,
                              hipStream_t stream)
{
    const float* hidden = (const float*)d_in[0];
    const float* topic  = (const float*)d_in[1];
    const float* enc    = (const float*)d_in[2];
    const float* W_h    = (const float*)d_in[3];
    const float* W_t    = (const float*)d_in[4];
    const float* W_e    = (const float*)d_in[5];
    const float* bvec   = (const float*)d_in[6];
    const float* vvec   = (const float*)d_in[7];
    float* out = (float*)d_out;

    float* P      = (float*)d_ws;
    float* R      = P + P_FLOATS;
    float* SPb    = R + R_FLOATS;
    _Float16* pA  = (_Float16*)(SPb + SP_FLOATS);
    _Float16* pB  = pA + PA_HALVES;

    pack_kernel<<<1344, 256, 0, stream>>>(hidden, topic, enc, W_h, W_t, W_e, pA, pB);
    gemm_kernel<<<640, 256, 0, stream>>>(pA, pB, P);
    reduce_kernel<<<640, 256, 0, stream>>>(P, bvec, R);
    score_kernel<<<dim3(8, 8, 8), 256, 0, stream>>>(R, vvec, SPb);
    softmax_kernel<<<128, 256, 0, stream>>>(SPb, out);
}

// Round 13
// 115.691 us; speedup vs baseline: 1.0765x; 1.0012x over previous
//
#include <hip/hip_runtime.h>
#include <hip/hip_fp16.h>

#define B_ 128
#define T_ 512
#define VT_ 2048
#define E_ 1024
#define D_ 1024

typedef _Float16 h8 __attribute__((ext_vector_type(8)));
typedef float f4 __attribute__((ext_vector_type(4)));

#define C2LE 2.8853900817779268f  // 2*log2(e)
#define L2E  1.4426950408889634f

static __device__ __forceinline__ float rcpf(float x) { return __builtin_amdgcn_rcpf(x); }
static __device__ __forceinline__ float ex2(float x)  { return __builtin_amdgcn_exp2f(x); }

// ---------------- workspace layout ----------------
// P  : float[8][640][1024]  split-K partials (rows 0-127 = X, 128-639 = Y)
// R  : float[640][1024]     reduced (+ C2LE*bias on X rows)
// SP : float[8][128][512]   per-d-chunk score partials
// pA : f16[640*2048]        A fragments (KB-dim 64)
// pB : f16[1M + 1M + 2M]    W_h^T, W_e^T, W_t^T fragments
#define P_FLOATS   (8 * 640 * 1024)
#define R_FLOATS   (640 * 1024)
#define SP_FLOATS  (8 * 128 * 512)
#define PA_HALVES  (640 * 2048)
#define PB_WH      0
#define PB_WE      1048576
#define PB_WT      2097152

// ---------- coalesced pack: 64x64 fp32 panel -> f16 MFMA fragments ----------
// A panel: rows = m (4 mb of 16), cols = k (2 kb of 32). Frag lane r=lane&15 -> m, g=lane>>4: k=g*8+j.
__device__ __forceinline__ void pack_panelA(const float* __restrict__ src, int ld,
                                            _Float16* __restrict__ dst, int mb_off, int kb_off,
                                            int pm, int pk, int tid, float lds[64][72])
{
    #pragma unroll
    for (int p = 0; p < 4; ++p) {
        int row = (tid >> 4) + p * 16, col = (tid & 15) * 4;
        *(f4*)&lds[row][col] = *(const f4*)&src[(size_t)(pm * 64 + row) * ld + pk * 64 + col];
    }
    __syncthreads();
    #pragma unroll
    for (int w = 0; w < 2; ++w) {
        int fl = w * 256 + tid;
        int f = fl >> 6, lane = fl & 63;
        int i = f >> 1, k2 = f & 1;
        int r = lane & 15, g = lane >> 4;
        const float* p = &lds[i * 16 + r][k2 * 32 + g * 8];
        h8 h;
        #pragma unroll
        for (int j = 0; j < 8; ++j) h[j] = (_Float16)p[j];
        int MB = mb_off + pm * 4 + i;
        int KB = kb_off + pk * 2 + k2;
        *(h8*)(dst + ((size_t)(MB * 64 + KB) * 64 + lane) * 8) = h;
    }
}

// B panel from W[K][1024]: rows = k (2 kb of 32), cols = n (4 nb of 16). Frag: n=r, k=g*8+j (transposed).
__device__ __forceinline__ void pack_panelB(const float* __restrict__ W,
                                            _Float16* __restrict__ dst, int KBdim,
                                            int pk, int pn, int tid, float lds[64][72])
{
    #pragma unroll
    for (int p = 0; p < 4; ++p) {
        int row = (tid >> 4) + p * 16, col = (tid & 15) * 4;
        *(f4*)&lds[row][col] = *(const f4*)&W[(size_t)(pk * 64 + row) * 1024 + pn * 64 + col];
    }
    __syncthreads();
    #pragma unroll
    for (int w = 0; w < 2; ++w) {
        int fl = w * 256 + tid;
        int f = fl >> 6, lane = fl & 63;
        int j = f >> 1, i2 = f & 1;
        int r = lane & 15, g = lane >> 4;
        h8 h;
        #pragma unroll
        for (int jj = 0; jj < 8; ++jj) h[jj] = (_Float16)lds[i2 * 32 + g * 8 + jj][j * 16 + r];
        int NB = pn * 4 + j;
        int KB = pk * 2 + i2;
        *(h8*)(dst + ((size_t)(NB * KBdim + KB) * 64 + lane) * 8) = h;
    }
}

__global__ __launch_bounds__(256) void pack_kernel(
    const float* __restrict__ hidden, const float* __restrict__ topic,
    const float* __restrict__ enc,
    const float* __restrict__ W_h, const float* __restrict__ W_t, const float* __restrict__ W_e,
    _Float16* __restrict__ pA, _Float16* __restrict__ pB)
{
    __shared__ float lds[64][72];
    const int bid = blockIdx.x, tid = threadIdx.x;
    if (bid < 32) {                         // hidden [128][1024] -> A kb 0..31
        int b = bid;        pack_panelA(hidden, 1024, pA, 0,  0, b >> 4, b & 15, tid, lds);
    } else if (bid < 64) {                  // enc [128][1024] -> A kb 32..63
        int b = bid - 32;   pack_panelA(enc,    1024, pA, 0, 32, b >> 4, b & 15, tid, lds);
    } else if (bid < 320) {                 // topic [512][2048] -> A mb 8..39
        int b = bid - 64;   pack_panelA(topic,  2048, pA, 8,  0, b >> 5, b & 31, tid, lds);
    } else if (bid < 576) {                 // W_h [1024][1024]
        int b = bid - 320;  pack_panelB(W_h, pB + PB_WH, 32, b >> 4, b & 15, tid, lds);
    } else if (bid < 832) {                 // W_e
        int b = bid - 576;  pack_panelB(W_e, pB + PB_WE, 32, b >> 4, b & 15, tid, lds);
    } else {                                // W_t [2048][1024]
        int b = bid - 832;  pack_panelB(W_t, pB + PB_WT, 64, b >> 4, b & 15, tid, lds);
    }
}

// fused GEMM, split-K=8, wave tile 32x64 (acc 2x4), XCD-swizzled so each XCD owns one
// K-slice s. Plain stores to P. unroll 2: caps in-flight loads at 12 (~100 VGPR, no spill).
__global__ __launch_bounds__(256, 3) void gemm_kernel(const _Float16* __restrict__ pA,
                                                      const _Float16* __restrict__ pB,
                                                      float* __restrict__ P)
{
    // bijective XCD swizzle: nwg=640, all blocks with lin%8==c get s=c
    const int lin = blockIdx.x;
    const int sw  = (lin & 7) * 80 + (lin >> 3);
    const int s   = sw / 80;
    const int rem = sw % 80;
    const int mt  = rem % 10;
    const int nt  = rem / 10;

    const int tid = threadIdx.x, wave = tid >> 6, lane = tid & 63;
    const int wm = (wave >> 1) * 32;   // 0 or 32
    const int wn = (wave & 1) * 64;    // 0 or 64
    const int r = lane & 15, g = lane >> 4;

    const int mb0 = mt * 4 + (wm >> 4);
    const int nb0 = (nt * 128 + wn) >> 4;
    const int kb0 = s * 8;

    const _Float16* Bp; int KB_B, kbB0;
    if (mt < 2) {  // X rows: s<4 -> hidden@W_h (A kb 0..31), s>=4 -> enc@W_e (A kb 32..63)
        if (kb0 < 32) { Bp = pB + PB_WH; kbB0 = kb0; }
        else          { Bp = pB + PB_WE; kbB0 = kb0 - 32; }
        KB_B = 32;
    } else { Bp = pB + PB_WT; kbB0 = kb0; KB_B = 64; }

    const _Float16* Ap = pA + ((size_t)(mb0 * 64 + kb0) * 64 + lane) * 8;
    const _Float16* Bq = Bp + ((size_t)(nb0 * KB_B + kbB0) * 64 + lane) * 8;
    const size_t aStrM = (size_t)64 * 512;        // mb -> mb+1
    const size_t bStrN = (size_t)KB_B * 512;      // nb -> nb+1

    f4 acc[2][4] = {};
    #pragma unroll 2
    for (int ks = 0; ks < 8; ++ks) {
        h8 a0 = *(const h8*)(Ap + (size_t)ks * 512);
        h8 a1 = *(const h8*)(Ap + aStrM + (size_t)ks * 512);
        h8 b0 = *(const h8*)(Bq + (size_t)ks * 512);
        h8 b1 = *(const h8*)(Bq + bStrN + (size_t)ks * 512);
        h8 b2 = *(const h8*)(Bq + 2 * bStrN + (size_t)ks * 512);
        h8 b3 = *(const h8*)(Bq + 3 * bStrN + (size_t)ks * 512);
        acc[0][0] = __builtin_amdgcn_mfma_f32_16x16x32_f16(a0, b0, acc[0][0], 0, 0, 0);
        acc[0][1] = __builtin_amdgcn_mfma_f32_16x16x32_f16(a0, b1, acc[0][1], 0, 0, 0);
        acc[0][2] = __builtin_amdgcn_mfma_f32_16x16x32_f16(a0, b2, acc[0][2], 0, 0, 0);
        acc[0][3] = __builtin_amdgcn_mfma_f32_16x16x32_f16(a0, b3, acc[0][3], 0, 0, 0);
        acc[1][0] = __builtin_amdgcn_mfma_f32_16x16x32_f16(a1, b0, acc[1][0], 0, 0, 0);
        acc[1][1] = __builtin_amdgcn_mfma_f32_16x16x32_f16(a1, b1, acc[1][1], 0, 0, 0);
        acc[1][2] = __builtin_amdgcn_mfma_f32_16x16x32_f16(a1, b2, acc[1][2], 0, 0, 0);
        acc[1][3] = __builtin_amdgcn_mfma_f32_16x16x32_f16(a1, b3, acc[1][3], 0, 0, 0);
    }

    // C/D layout: col = lane&15, row = (lane>>4)*4 + q
    float* Pp = P + ((size_t)s * 640 + mt * 64 + wm + g * 4) * 1024 + nt * 128 + wn + r;
    #pragma unroll
    for (int i = 0; i < 2; ++i)
        #pragma unroll
        for (int j = 0; j < 4; ++j)
            #pragma unroll
            for (int q = 0; q < 4; ++q)
                Pp[(size_t)(i * 16 + q) * 1024 + j * 16] = C2LE * acc[i][j][q];
}

// R[row][d] = sum_z P[z][row][d] + (row<128 ? C2LE*bias[d] : 0)
__global__ __launch_bounds__(256) void reduce_kernel(const float* __restrict__ P,
                                                     const float* __restrict__ bias,
                                                     float* __restrict__ R)
{
    const int row = blockIdx.x, tid = threadIdx.x;
    const size_t off = (size_t)row * 1024 + tid * 4;
    const size_t PS = (size_t)640 * 1024;
    f4 acc = *(const f4*)&P[off];
    #pragma unroll
    for (int z = 1; z < 8; ++z) acc += *(const f4*)&P[off + (size_t)z * PS];
    if (row < 128) {
        f4 bb = *(const f4*)&bias[tid * 4];
        acc += bb * C2LE;
    }
    *(f4*)&R[off] = acc;
}

// SP[z][b][t] = sum_{d in chunk z} v_d * rcp(exp2(X+Y) + 1)
__global__ __launch_bounds__(256) void score_kernel(const float* __restrict__ R,
                                                    const float* __restrict__ v,
                                                    float* __restrict__ SP)
{
    __shared__ float Xs[16][128];   // XOR-16 swizzle on 16B units
    __shared__ float Ys[64][128];
    __shared__ float vs[128];

    const int tid = threadIdx.x;
    const int b0 = blockIdx.x * 16;
    const int t0 = blockIdx.y * 64;
    const int d0 = blockIdx.z * 128;

    #pragma unroll
    for (int i = 0; i < 8; ++i) {
        int idx = tid + i * 256;
        int row = idx >> 5, c4 = idx & 31;
        f4 vv = *(const f4*)&R[(size_t)(128 + t0 + row) * 1024 + d0 + c4 * 4];
        *(f4*)&Ys[row][(c4 ^ (row & 15)) * 4] = vv;
    }
    #pragma unroll
    for (int i = 0; i < 2; ++i) {
        int idx = tid + i * 256;
        int row = idx >> 5, c4 = idx & 31;
        f4 vv = *(const f4*)&R[(size_t)(b0 + row) * 1024 + d0 + c4 * 4];
        *(f4*)&Xs[row][(c4 ^ (row & 15)) * 4] = vv;
    }
    if (tid < 32) *(f4*)&vs[tid * 4] = *(const f4*)&v[d0 + tid * 4];
    __syncthreads();

    const int tq = tid & 31, bq = tid >> 5;
    const int sx0 = bq & 15, sx1 = (bq + 8) & 15, sy = tq & 15;
    float a00 = 0.f, a01 = 0.f, a10 = 0.f, a11 = 0.f;

    for (int dd = 0; dd < 32; ++dd) {
        f4 xa = *(const f4*)&Xs[bq]     [(dd ^ sx0) * 4];
        f4 xb = *(const f4*)&Xs[bq + 8] [(dd ^ sx1) * 4];
        f4 ya = *(const f4*)&Ys[tq]     [(dd ^ sy) * 4];
        f4 yb = *(const f4*)&Ys[tq + 32][(dd ^ sy) * 4];
        f4 vv = *(const f4*)&vs[dd * 4];
        #pragma unroll
        for (int j = 0; j < 4; ++j) {
            float e;
            e = ex2(xa[j] + ya[j]); a00 += vv[j] * rcpf(e + 1.0f);
            e = ex2(xa[j] + yb[j]); a01 += vv[j] * rcpf(e + 1.0f);
            e = ex2(xb[j] + ya[j]); a10 += vv[j] * rcpf(e + 1.0f);
            e = ex2(xb[j] + yb[j]); a11 += vv[j] * rcpf(e + 1.0f);
        }
    }

    float* sp = SP + (size_t)blockIdx.z * (B_ * T_);
    sp[(size_t)(b0 + bq)     * T_ + t0 + tq]      = a00;
    sp[(size_t)(b0 + bq)     * T_ + t0 + tq + 32] = a01;
    sp[(size_t)(b0 + bq + 8) * T_ + t0 + tq]      = a10;
    sp[(size_t)(b0 + bq + 8) * T_ + t0 + tq + 32] = a11;
}

// softmax over t of score = -2 * sum_z SP[z][b][t]  (constant sum(v) cancels)
__global__ __launch_bounds__(256) void softmax_kernel(
    const float* __restrict__ SP, float* __restrict__ out)
{
    const int b = blockIdx.x, tid = threadIdx.x;
    float s0 = 0.f, s1 = 0.f;
    #pragma unroll
    for (int z = 0; z < 8; ++z) {
        s0 += SP[(size_t)z * B_ * T_ + (size_t)b * T_ + tid];
        s1 += SP[(size_t)z * B_ * T_ + (size_t)b * T_ + tid + 256];
    }
    s0 *= -2.0f; s1 *= -2.0f;

    float m = fmaxf(s0, s1);
    #pragma unroll
    for (int off = 32; off >= 1; off >>= 1) m = fmaxf(m, __shfl_xor(m, off));
    __shared__ float red[4];
    __shared__ float red2[4];
    const int wv = tid >> 6;
    if ((tid & 63) == 0) red[wv] = m;
    __syncthreads();
    m = fmaxf(fmaxf(red[0], red[1]), fmaxf(red[2], red[3]));

    float e0 = ex2((s0 - m) * L2E);
    float e1 = ex2((s1 - m) * L2E);
    float sum = e0 + e1;
    #pragma unroll
    for (int off = 32; off >= 1; off >>= 1) sum += __shfl_xor(sum, off);
    if ((tid & 63) == 0) red2[wv] = sum;
    __syncthreads();
    sum = red2[0] + red2[1] + red2[2] + red2[3];

    const float rs = rcpf(sum);
    out[(size_t)b * T_ + tid]       = e0 * rs;
    out[(size_t)b * T_ + tid + 256] = e1 * rs;
}

extern "C" void kernel_launch(void* const* d_in, const int* in_sizes, int n_in,
                              void* d_out, int out_size, void* d_ws, size_t ws_size,
                              hipStream_t stream)
{
    const float* hidden = (const float*)d_in[0];
    const float* topic  = (const float*)d_in[1];
    const float* enc    = (const float*)d_in[2];
    const float* W_h    = (const float*)d_in[3];
    const float* W_t    = (const float*)d_in[4];
    const float* W_e    = (const float*)d_in[5];
    const float* bvec   = (const float*)d_in[6];
    const float* vvec   = (const float*)d_in[7];
    float* out = (float*)d_out;

    float* P      = (float*)d_ws;
    float* R      = P + P_FLOATS;
    float* SPb    = R + R_FLOATS;
    _Float16* pA  = (_Float16*)(SPb + SP_FLOATS);
    _Float16* pB  = pA + PA_HALVES;

    pack_kernel<<<1344, 256, 0, stream>>>(hidden, topic, enc, W_h, W_t, W_e, pA, pB);
    gemm_kernel<<<640, 256, 0, stream>>>(pA, pB, P);
    reduce_kernel<<<640, 256, 0, stream>>>(P, bvec, R);
    score_kernel<<<dim3(8, 8, 8), 256, 0, stream>>>(R, vvec, SPb);
    softmax_kernel<<<128, 256, 0, stream>>>(SPb, out);
}

// Round 14
// 114.397 us; speedup vs baseline: 1.0886x; 1.0113x over previous
//
#include <hip/hip_runtime.h>
#include <hip/hip_fp16.h>

#define B_ 128
#define T_ 512
#define VT_ 2048
#define E_ 1024
#define D_ 1024

typedef _Float16 h8 __attribute__((ext_vector_type(8)));
typedef float f4 __attribute__((ext_vector_type(4)));

#define C2LE 2.8853900817779268f  // 2*log2(e)
#define L2E  1.4426950408889634f

static __device__ __forceinline__ float rcpf(float x) { return __builtin_amdgcn_rcpf(x); }
static __device__ __forceinline__ float ex2(float x)  { return __builtin_amdgcn_exp2f(x); }

// ---------------- workspace layout ----------------
// P  : float[8][640][1024]  split-K partials (rows 0-127 = X, 128-639 = Y)
// R  : float[640][1024]     reduced (+ C2LE*bias on X rows)
// SP : float[8][128][512]   per-d-chunk score partials
// pA : f16[640*2048]        A fragments (KB-dim 64)
// pB : f16[1M + 1M + 2M]    W_h^T, W_e^T, W_t^T fragments
#define P_FLOATS   (8 * 640 * 1024)
#define R_FLOATS   (640 * 1024)
#define SP_FLOATS  (8 * 128 * 512)
#define PA_HALVES  (640 * 2048)
#define PB_WH      0
#define PB_WE      1048576
#define PB_WT      2097152

// ---------- coalesced pack: 64x64 fp32 panel -> f16 MFMA fragments ----------
__device__ __forceinline__ void pack_panelA(const float* __restrict__ src, int ld,
                                            _Float16* __restrict__ dst, int mb_off, int kb_off,
                                            int pm, int pk, int tid, float lds[64][72])
{
    #pragma unroll
    for (int p = 0; p < 4; ++p) {
        int row = (tid >> 4) + p * 16, col = (tid & 15) * 4;
        *(f4*)&lds[row][col] = *(const f4*)&src[(size_t)(pm * 64 + row) * ld + pk * 64 + col];
    }
    __syncthreads();
    #pragma unroll
    for (int w = 0; w < 2; ++w) {
        int fl = w * 256 + tid;
        int f = fl >> 6, lane = fl & 63;
        int i = f >> 1, k2 = f & 1;
        int r = lane & 15, g = lane >> 4;
        const float* p = &lds[i * 16 + r][k2 * 32 + g * 8];
        h8 h;
        #pragma unroll
        for (int j = 0; j < 8; ++j) h[j] = (_Float16)p[j];
        int MB = mb_off + pm * 4 + i;
        int KB = kb_off + pk * 2 + k2;
        *(h8*)(dst + ((size_t)(MB * 64 + KB) * 64 + lane) * 8) = h;
    }
}

__device__ __forceinline__ void pack_panelB(const float* __restrict__ W,
                                            _Float16* __restrict__ dst, int KBdim,
                                            int pk, int pn, int tid, float lds[64][72])
{
    #pragma unroll
    for (int p = 0; p < 4; ++p) {
        int row = (tid >> 4) + p * 16, col = (tid & 15) * 4;
        *(f4*)&lds[row][col] = *(const f4*)&W[(size_t)(pk * 64 + row) * 1024 + pn * 64 + col];
    }
    __syncthreads();
    #pragma unroll
    for (int w = 0; w < 2; ++w) {
        int fl = w * 256 + tid;
        int f = fl >> 6, lane = fl & 63;
        int j = f >> 1, i2 = f & 1;
        int r = lane & 15, g = lane >> 4;
        h8 h;
        #pragma unroll
        for (int jj = 0; jj < 8; ++jj) h[jj] = (_Float16)lds[i2 * 32 + g * 8 + jj][j * 16 + r];
        int NB = pn * 4 + j;
        int KB = pk * 2 + i2;
        *(h8*)(dst + ((size_t)(NB * KBdim + KB) * 64 + lane) * 8) = h;
    }
}

__global__ __launch_bounds__(256) void pack_kernel(
    const float* __restrict__ hidden, const float* __restrict__ topic,
    const float* __restrict__ enc,
    const float* __restrict__ W_h, const float* __restrict__ W_t, const float* __restrict__ W_e,
    _Float16* __restrict__ pA, _Float16* __restrict__ pB)
{
    __shared__ float lds[64][72];
    const int bid = blockIdx.x, tid = threadIdx.x;
    if (bid < 32) {
        int b = bid;        pack_panelA(hidden, 1024, pA, 0,  0, b >> 4, b & 15, tid, lds);
    } else if (bid < 64) {
        int b = bid - 32;   pack_panelA(enc,    1024, pA, 0, 32, b >> 4, b & 15, tid, lds);
    } else if (bid < 320) {
        int b = bid - 64;   pack_panelA(topic,  2048, pA, 8,  0, b >> 5, b & 31, tid, lds);
    } else if (bid < 576) {
        int b = bid - 320;  pack_panelB(W_h, pB + PB_WH, 32, b >> 4, b & 15, tid, lds);
    } else if (bid < 832) {
        int b = bid - 576;  pack_panelB(W_e, pB + PB_WE, 32, b >> 4, b & 15, tid, lds);
    } else {
        int b = bid - 832;  pack_panelB(W_t, pB + PB_WT, 64, b >> 4, b & 15, tid, lds);
    }
}

// fused GEMM, split-K=8, wave tile 32x64 (acc 2x4), XCD-swizzled.
// launch_bounds(256) WITHOUT min-wave arg: no forced VGPR cap -> no spill risk.
__global__ __launch_bounds__(256) void gemm_kernel(const _Float16* __restrict__ pA,
                                                   const _Float16* __restrict__ pB,
                                                   float* __restrict__ P)
{
    const int lin = blockIdx.x;
    const int sw  = (lin & 7) * 80 + (lin >> 3);
    const int s   = sw / 80;
    const int rem = sw % 80;
    const int mt  = rem % 10;
    const int nt  = rem / 10;

    const int tid = threadIdx.x, wave = tid >> 6, lane = tid & 63;
    const int wm = (wave >> 1) * 32;
    const int wn = (wave & 1) * 64;
    const int r = lane & 15, g = lane >> 4;

    const int mb0 = mt * 4 + (wm >> 4);
    const int nb0 = (nt * 128 + wn) >> 4;
    const int kb0 = s * 8;

    const _Float16* Bp; int KB_B, kbB0;
    if (mt < 2) {
        if (kb0 < 32) { Bp = pB + PB_WH; kbB0 = kb0; }
        else          { Bp = pB + PB_WE; kbB0 = kb0 - 32; }
        KB_B = 32;
    } else { Bp = pB + PB_WT; kbB0 = kb0; KB_B = 64; }

    const _Float16* Ap = pA + ((size_t)(mb0 * 64 + kb0) * 64 + lane) * 8;
    const _Float16* Bq = Bp + ((size_t)(nb0 * KB_B + kbB0) * 64 + lane) * 8;
    const size_t aStrM = (size_t)64 * 512;
    const size_t bStrN = (size_t)KB_B * 512;

    f4 acc[2][4] = {};
    #pragma unroll 2
    for (int ks = 0; ks < 8; ++ks) {
        h8 a0 = *(const h8*)(Ap + (size_t)ks * 512);
        h8 a1 = *(const h8*)(Ap + aStrM + (size_t)ks * 512);
        h8 b0 = *(const h8*)(Bq + (size_t)ks * 512);
        h8 b1 = *(const h8*)(Bq + bStrN + (size_t)ks * 512);
        h8 b2 = *(const h8*)(Bq + 2 * bStrN + (size_t)ks * 512);
        h8 b3 = *(const h8*)(Bq + 3 * bStrN + (size_t)ks * 512);
        acc[0][0] = __builtin_amdgcn_mfma_f32_16x16x32_f16(a0, b0, acc[0][0], 0, 0, 0);
        acc[0][1] = __builtin_amdgcn_mfma_f32_16x16x32_f16(a0, b1, acc[0][1], 0, 0, 0);
        acc[0][2] = __builtin_amdgcn_mfma_f32_16x16x32_f16(a0, b2, acc[0][2], 0, 0, 0);
        acc[0][3] = __builtin_amdgcn_mfma_f32_16x16x32_f16(a0, b3, acc[0][3], 0, 0, 0);
        acc[1][0] = __builtin_amdgcn_mfma_f32_16x16x32_f16(a1, b0, acc[1][0], 0, 0, 0);
        acc[1][1] = __builtin_amdgcn_mfma_f32_16x16x32_f16(a1, b1, acc[1][1], 0, 0, 0);
        acc[1][2] = __builtin_amdgcn_mfma_f32_16x16x32_f16(a1, b2, acc[1][2], 0, 0, 0);
        acc[1][3] = __builtin_amdgcn_mfma_f32_16x16x32_f16(a1, b3, acc[1][3], 0, 0, 0);
    }

    float* Pp = P + ((size_t)s * 640 + mt * 64 + wm + g * 4) * 1024 + nt * 128 + wn + r;
    #pragma unroll
    for (int i = 0; i < 2; ++i)
        #pragma unroll
        for (int j = 0; j < 4; ++j)
            #pragma unroll
            for (int q = 0; q < 4; ++q)
                Pp[(size_t)(i * 16 + q) * 1024 + j * 16] = C2LE * acc[i][j][q];
}

// R[row][d] = sum_z P[z][row][d] + (row<128 ? C2LE*bias[d] : 0)
__global__ __launch_bounds__(256) void reduce_kernel(const float* __restrict__ P,
                                                     const float* __restrict__ bias,
                                                     float* __restrict__ R)
{
    const int row = blockIdx.x, tid = threadIdx.x;
    const size_t off = (size_t)row * 1024 + tid * 4;
    const size_t PS = (size_t)640 * 1024;
    f4 acc = *(const f4*)&P[off];
    #pragma unroll
    for (int z = 1; z < 8; ++z) acc += *(const f4*)&P[off + (size_t)z * PS];
    if (row < 128) {
        f4 bb = *(const f4*)&bias[tid * 4];
        acc += bb * C2LE;
    }
    *(f4*)&R[off] = acc;
}

// paired sigmoid-dot: v0*s(x0)+v1*s(x1) = (vsum + v0*B + v1*A) / ((1+A)(1+B)),
// A=exp2(x0),B=exp2(x1). One rcp per two elements: trans ops 1024->768 per thread.
static __device__ __forceinline__ float pair_term(float x0, float x1,
                                                  float v0, float v1, float vsum)
{
    float A = ex2(x0), B = ex2(x1);
    float t = 1.0f + A;
    float den = __builtin_fmaf(t, B, t);                    // (1+A)(1+B)
    float num = __builtin_fmaf(v0, B, __builtin_fmaf(v1, A, vsum));
    return num * rcpf(den);
}

// SP[z][b][t] = sum_{d in chunk z} v_d / (1 + exp2(X+Y))
__global__ __launch_bounds__(256) void score_kernel(const float* __restrict__ R,
                                                    const float* __restrict__ v,
                                                    float* __restrict__ SP)
{
    __shared__ float Xs[16][128];   // XOR-16 swizzle on 16B units
    __shared__ float Ys[64][128];
    __shared__ float vs[128];
    __shared__ float vsum[64];      // pair sums v[2p]+v[2p+1]

    const int tid = threadIdx.x;
    const int b0 = blockIdx.x * 16;
    const int t0 = blockIdx.y * 64;
    const int d0 = blockIdx.z * 128;

    #pragma unroll
    for (int i = 0; i < 8; ++i) {
        int idx = tid + i * 256;
        int row = idx >> 5, c4 = idx & 31;
        f4 vv = *(const f4*)&R[(size_t)(128 + t0 + row) * 1024 + d0 + c4 * 4];
        *(f4*)&Ys[row][(c4 ^ (row & 15)) * 4] = vv;
    }
    #pragma unroll
    for (int i = 0; i < 2; ++i) {
        int idx = tid + i * 256;
        int row = idx >> 5, c4 = idx & 31;
        f4 vv = *(const f4*)&R[(size_t)(b0 + row) * 1024 + d0 + c4 * 4];
        *(f4*)&Xs[row][(c4 ^ (row & 15)) * 4] = vv;
    }
    if (tid < 32) *(f4*)&vs[tid * 4] = *(const f4*)&v[d0 + tid * 4];
    if (tid >= 64 && tid < 128) {
        int p = tid - 64;
        vsum[p] = v[d0 + 2 * p] + v[d0 + 2 * p + 1];
    }
    __syncthreads();

    const int tq = tid & 31, bq = tid >> 5;
    const int sx0 = bq & 15, sx1 = (bq + 8) & 15, sy = tq & 15;
    float a00 = 0.f, a01 = 0.f, a10 = 0.f, a11 = 0.f;

    for (int dd = 0; dd < 32; ++dd) {
        f4 xa = *(const f4*)&Xs[bq]     [(dd ^ sx0) * 4];
        f4 xb = *(const f4*)&Xs[bq + 8] [(dd ^ sx1) * 4];
        f4 ya = *(const f4*)&Ys[tq]     [(dd ^ sy) * 4];
        f4 yb = *(const f4*)&Ys[tq + 32][(dd ^ sy) * 4];
        f4 vv = *(const f4*)&vs[dd * 4];
        float vs0 = vsum[dd * 2], vs1 = vsum[dd * 2 + 1];

        a00 += pair_term(xa[0] + ya[0], xa[1] + ya[1], vv[0], vv[1], vs0)
             + pair_term(xa[2] + ya[2], xa[3] + ya[3], vv[2], vv[3], vs1);
        a01 += pair_term(xa[0] + yb[0], xa[1] + yb[1], vv[0], vv[1], vs0)
             + pair_term(xa[2] + yb[2], xa[3] + yb[3], vv[2], vv[3], vs1);
        a10 += pair_term(xb[0] + ya[0], xb[1] + ya[1], vv[0], vv[1], vs0)
             + pair_term(xb[2] + ya[2], xb[3] + ya[3], vv[2], vv[3], vs1);
        a11 += pair_term(xb[0] + yb[0], xb[1] + yb[1], vv[0], vv[1], vs0)
             + pair_term(xb[2] + yb[2], xb[3] + yb[3], vv[2], vv[3], vs1);
    }

    float* sp = SP + (size_t)blockIdx.z * (B_ * T_);
    sp[(size_t)(b0 + bq)     * T_ + t0 + tq]      = a00;
    sp[(size_t)(b0 + bq)     * T_ + t0 + tq + 32] = a01;
    sp[(size_t)(b0 + bq + 8) * T_ + t0 + tq]      = a10;
    sp[(size_t)(b0 + bq + 8) * T_ + t0 + tq + 32] = a11;
}

// softmax over t of score = -2 * sum_z SP[z][b][t]  (constant sum(v) cancels)
__global__ __launch_bounds__(256) void softmax_kernel(
    const float* __restrict__ SP, float* __restrict__ out)
{
    const int b = blockIdx.x, tid = threadIdx.x;
    float s0 = 0.f, s1 = 0.f;
    #pragma unroll
    for (int z = 0; z < 8; ++z) {
        s0 += SP[(size_t)z * B_ * T_ + (size_t)b * T_ + tid];
        s1 += SP[(size_t)z * B_ * T_ + (size_t)b * T_ + tid + 256];
    }
    s0 *= -2.0f; s1 *= -2.0f;

    float m = fmaxf(s0, s1);
    #pragma unroll
    for (int off = 32; off >= 1; off >>= 1) m = fmaxf(m, __shfl_xor(m, off));
    __shared__ float red[4];
    __shared__ float red2[4];
    const int wv = tid >> 6;
    if ((tid & 63) == 0) red[wv] = m;
    __syncthreads();
    m = fmaxf(fmaxf(red[0], red[1]), fmaxf(red[2], red[3]));

    float e0 = ex2((s0 - m) * L2E);
    float e1 = ex2((s1 - m) * L2E);
    float sum = e0 + e1;
    #pragma unroll
    for (int off = 32; off >= 1; off >>= 1) sum += __shfl_xor(sum, off);
    if ((tid & 63) == 0) red2[wv] = sum;
    __syncthreads();
    sum = red2[0] + red2[1] + red2[2] + red2[3];

    const float rs = rcpf(sum);
    out[(size_t)b * T_ + tid]       = e0 * rs;
    out[(size_t)b * T_ + tid + 256] = e1 * rs;
}

extern "C" void kernel_launch(void* const* d_in, const int* in_sizes, int n_in,
                              void* d_out, int out_size, void* d_ws, size_t ws_size,
                              hipStream_t stream)
{
    const float* hidden = (const float*)d_in[0];
    const float* topic  = (const float*)d_in[1];
    const float* enc    = (const float*)d_in[2];
    const float* W_h    = (const float*)d_in[3];
    const float* W_t    = (const float*)d_in[4];
    const float* W_e    = (const float*)d_in[5];
    const float* bvec   = (const float*)d_in[6];
    const float* vvec   = (const float*)d_in[7];
    float* out = (float*)d_out;

    float* P      = (float*)d_ws;
    float* R      = P + P_FLOATS;
    float* SPb    = R + R_FLOATS;
    _Float16* pA  = (_Float16*)(SPb + SP_FLOATS);
    _Float16* pB  = pA + PA_HALVES;

    pack_kernel<<<1344, 256, 0, stream>>>(hidden, topic, enc, W_h, W_t, W_e, pA, pB);
    gemm_kernel<<<640, 256, 0, stream>>>(pA, pB, P);
    reduce_kernel<<<640, 256, 0, stream>>>(P, bvec, R);
    score_kernel<<<dim3(8, 8, 8), 256, 0, stream>>>(R, vvec, SPb);
    softmax_kernel<<<128, 256, 0, stream>>>(SPb, out);
}